// Round 1
// baseline (376.663 us; speedup 1.0000x reference)
//
#include <hip/hip_runtime.h>
#include <stdint.h>

typedef __attribute__((ext_vector_type(8))) short short8;
typedef __attribute__((ext_vector_type(8))) unsigned short ushort8;
typedef __attribute__((ext_vector_type(4))) float f32x4;

// ---------- helpers ----------

__device__ __forceinline__ unsigned short f2bf_rne(float f) {
    // round-to-nearest-even fp32 -> bf16 (inputs are finite normals)
    unsigned int u = __builtin_bit_cast(unsigned int, f);
    return (unsigned short)((u + 0x7FFFu + ((u >> 16) & 1u)) >> 16);
}

__device__ __forceinline__ void async_copy16(const void* g, void* l) {
    // global -> LDS direct, 16B per lane; LDS dest must be wave-uniform base + lane*16
    __builtin_amdgcn_global_load_lds(
        (__attribute__((address_space(1))) void*)g,
        (__attribute__((address_space(3))) void*)l,
        16, 0, 0);
}

// ---------- pre-pass: x (f32) -> bf16 ----------

__global__ void lb_cvt_x(const float* __restrict__ x, ushort8* __restrict__ xb, long n8) {
    long i = (long)blockIdx.x * blockDim.x + threadIdx.x;
    long stride = (long)gridDim.x * blockDim.x;
    for (; i < n8; i += stride) {
        const float4* p = (const float4*)x + i * 2;
        float4 a = p[0], b = p[1];
        ushort8 r;
        r[0] = f2bf_rne(a.x); r[1] = f2bf_rne(a.y); r[2] = f2bf_rne(a.z); r[3] = f2bf_rne(a.w);
        r[4] = f2bf_rne(b.x); r[5] = f2bf_rne(b.y); r[6] = f2bf_rne(b.z); r[7] = f2bf_rne(b.w);
        xb[i] = r;
    }
}

// ---------- pre-pass: w (f32) -> binarized bf16 {0,1} ----------

__global__ void lb_bin_w(const float* __restrict__ w, ushort8* __restrict__ wb, long n8) {
    long i = (long)blockIdx.x * blockDim.x + threadIdx.x;
    long stride = (long)gridDim.x * blockDim.x;
    for (; i < n8; i += stride) {
        const float4* p = (const float4*)w + i * 2;
        float4 a = p[0], b = p[1];
        ushort8 r;
        // round-half-even of uniform[0,1): 1 iff w > 0.5 (0.5 itself rounds to 0)
        r[0] = (a.x > 0.5f) ? 0x3F80u : 0u; r[1] = (a.y > 0.5f) ? 0x3F80u : 0u;
        r[2] = (a.z > 0.5f) ? 0x3F80u : 0u; r[3] = (a.w > 0.5f) ? 0x3F80u : 0u;
        r[4] = (b.x > 0.5f) ? 0x3F80u : 0u; r[5] = (b.y > 0.5f) ? 0x3F80u : 0u;
        r[6] = (b.z > 0.5f) ? 0x3F80u : 0u; r[7] = (b.w > 0.5f) ? 0x3F80u : 0u;
        wb[i] = r;
    }
}

// ---------- main GEMM: C[m][n] = sum_k A[m][k]*B[n][k] + bias[n] ----------
// m97 structure: 128x128 tile, BK=64, 4 waves (2x2), 16x16x32 bf16 MFMA,
// global_load_lds width 16, linear LDS, 2 barriers per K-step.

#define BM 128
#define BN 128
#define BK 64

__global__ __launch_bounds__(256) void lb_gemm_bf16(
    const unsigned short* __restrict__ A,  // M x K bf16 bits
    const unsigned short* __restrict__ B,  // N x K bf16 bits (binarized weight)
    const float* __restrict__ bias,
    float* __restrict__ C,
    int M, int N, int K)
{
    __shared__ unsigned short As[BM * BK];
    __shared__ unsigned short Bs[BN * BK];

    const int tid  = threadIdx.x;
    const int lane = tid & 63;
    const int wave = tid >> 6;          // 0..3
    const int wr   = wave >> 1;         // wave row (0..1) -> 64 rows each
    const int wc   = wave & 1;          // wave col (0..1) -> 64 cols each

    // XCD-aware bijective swizzle (nwg % 8 == 0 here)
    int nwg = gridDim.x;
    int bid = blockIdx.x;
    if ((nwg & 7) == 0) {
        int cpx = nwg >> 3;
        bid = (bid & 7) * cpx + (bid >> 3);
    }
    const int ntiles = N / BN;
    const int mt = bid / ntiles, nt = bid % ntiles;
    const int brow = mt * BM, bcol = nt * BN;

    // staging: thread t covers LDS bytes c*4096 + t*16 for chunk c=0..3
    const int sr = tid >> 3;            // 0..31 : row within 32-row chunk
    const int sc = (tid & 7) * 8;       // element col (0,8,..,56)
    const unsigned short* Ag = A + (long)(brow + sr) * K + sc;
    const unsigned short* Bg = B + (long)(bcol + sr) * K + sc;
    unsigned short* AsD = &As[(size_t)tid * 8];   // == (sr*64 + sc) elements... per-chunk offset added below
    unsigned short* BsD = &Bs[(size_t)tid * 8];

    // fragment addressing
    const int fr = lane & 15;           // A-row / B-col / C-col
    const int fq = lane >> 4;           // k-subgroup 0..3
    const unsigned short* AsP = &As[(size_t)(wr * 64 + fr) * BK + fq * 8];
    const unsigned short* BsP = &Bs[(size_t)(wc * 64 + fr) * BK + fq * 8];

    f32x4 acc[4][4];
#pragma unroll
    for (int i = 0; i < 4; ++i)
#pragma unroll
        for (int j = 0; j < 4; ++j)
            acc[i][j] = (f32x4){0.f, 0.f, 0.f, 0.f};

    const int nk = K / BK;
    for (int kt = 0; kt < nk; ++kt) {
        const unsigned short* ag = Ag + kt * BK;
        const unsigned short* bg = Bg + kt * BK;
#pragma unroll
        for (int c = 0; c < 4; ++c)
            async_copy16(ag + (long)c * 32 * K, AsD + (size_t)c * 2048);
#pragma unroll
        for (int c = 0; c < 4; ++c)
            async_copy16(bg + (long)c * 32 * K, BsD + (size_t)c * 2048);

        __syncthreads();   // drains vmcnt + barrier: tiles visible

#pragma unroll
        for (int kk = 0; kk < BK / 32; ++kk) {
            short8 af[4], bfr[4];
#pragma unroll
            for (int m = 0; m < 4; ++m)
                af[m] = *(const short8*)(AsP + (size_t)(m * 16) * BK + kk * 32);
#pragma unroll
            for (int n = 0; n < 4; ++n)
                bfr[n] = *(const short8*)(BsP + (size_t)(n * 16) * BK + kk * 32);
#pragma unroll
            for (int m = 0; m < 4; ++m)
#pragma unroll
                for (int n = 0; n < 4; ++n)
                    acc[m][n] = __builtin_amdgcn_mfma_f32_16x16x32_bf16(af[m], bfr[n], acc[m][n], 0, 0, 0);
        }

        __syncthreads();   // before next stage overwrites LDS
    }

    // epilogue: C/D layout col = lane&15, row = (lane>>4)*4 + reg  [m89/m91]
    float bn[4];
#pragma unroll
    for (int n = 0; n < 4; ++n)
        bn[n] = bias[bcol + wc * 64 + n * 16 + fr];

#pragma unroll
    for (int m = 0; m < 4; ++m) {
#pragma unroll
        for (int n = 0; n < 4; ++n) {
#pragma unroll
            for (int j = 0; j < 4; ++j) {
                int row = brow + wr * 64 + m * 16 + fq * 4 + j;
                int col = bcol + wc * 64 + n * 16 + fr;
                C[(long)row * N + col] = acc[m][n][j] + bn[n];
            }
        }
    }
}

// ---------- fallback (only if d_ws too small): correct fp32 tiled GEMM ----------

__global__ __launch_bounds__(256) void lb_gemm_fb(
    const float* __restrict__ x, const float* __restrict__ w,
    const float* __restrict__ bias, float* __restrict__ C,
    int M, int N, int K)
{
    __shared__ float As[16][65];
    __shared__ float Bs[16][65];
    const int tid = threadIdx.x;
    const int tx = tid & 15, ty = tid >> 4;
    const int brow = blockIdx.y * 64, bcol = blockIdx.x * 64;

    float acc[4][4] = {};
    for (int kt = 0; kt < K; kt += 16) {
        for (int i = tid; i < 64 * 16; i += 256) {
            int r = i >> 4, k = i & 15;
            As[k][r] = x[(long)(brow + r) * K + kt + k];
        }
        for (int i = tid; i < 64 * 16; i += 256) {
            int n = i >> 4, k = i & 15;
            Bs[k][n] = (w[(long)(bcol + n) * K + kt + k] > 0.5f) ? 1.f : 0.f;
        }
        __syncthreads();
#pragma unroll
        for (int k = 0; k < 16; ++k) {
            float a[4], b[4];
#pragma unroll
            for (int i = 0; i < 4; ++i) a[i] = As[k][ty * 4 + i];
#pragma unroll
            for (int j = 0; j < 4; ++j) b[j] = Bs[k][tx * 4 + j];
#pragma unroll
            for (int i = 0; i < 4; ++i)
#pragma unroll
                for (int j = 0; j < 4; ++j)
                    acc[i][j] += a[i] * b[j];
        }
        __syncthreads();
    }
#pragma unroll
    for (int i = 0; i < 4; ++i)
#pragma unroll
        for (int j = 0; j < 4; ++j)
            C[(long)(brow + ty * 4 + i) * N + bcol + tx * 4 + j] = acc[i][j] + bias[bcol + tx * 4 + j];
}

// ---------- launcher ----------

extern "C" void kernel_launch(void* const* d_in, const int* in_sizes, int n_in,
                              void* d_out, int out_size, void* d_ws, size_t ws_size,
                              hipStream_t stream) {
    const float* x    = (const float*)d_in[0];
    const float* w    = (const float*)d_in[1];
    const float* bias = (const float*)d_in[2];
    float* out = (float*)d_out;

    const int N = in_sizes[2];                 // 4096
    const int K = in_sizes[1] / N;             // 4096
    const int M = in_sizes[0] / K;             // 8192

    const size_t need = ((size_t)M * K + (size_t)N * K) * sizeof(unsigned short);
    const bool ok = (ws_size >= need) && (M % BM == 0) && (N % BN == 0) && (K % BK == 0)
                    && (K % 8 == 0);

    if (ok) {
        unsigned short* xb = (unsigned short*)d_ws;
        unsigned short* wb = xb + (size_t)M * K;

        long nx8 = (long)M * K / 8;
        long nw8 = (long)N * K / 8;
        lb_cvt_x<<<2048, 256, 0, stream>>>(x, (ushort8*)xb, nx8);
        lb_bin_w<<<2048, 256, 0, stream>>>(w, (ushort8*)wb, nw8);

        dim3 grid((M / BM) * (N / BN));        // 64*32 = 2048, %8 == 0
        lb_gemm_bf16<<<grid, 256, 0, stream>>>(xb, wb, bias, out, M, N, K);
    } else {
        dim3 grid(N / 64, M / 64);
        lb_gemm_fb<<<grid, 256, 0, stream>>>(x, w, bias, out, M, N, K);
    }
}

// Round 2
// 274.447 us; speedup vs baseline: 1.3724x; 1.3724x over previous
//
#include <hip/hip_runtime.h>
#include <stdint.h>

typedef __attribute__((ext_vector_type(8))) short short8;
typedef __attribute__((ext_vector_type(8))) unsigned short ushort8;
typedef __attribute__((ext_vector_type(4))) float f32x4;

// ---------- helpers ----------

__device__ __forceinline__ unsigned short f2bf_rne(float f) {
    unsigned int u = __builtin_bit_cast(unsigned int, f);
    return (unsigned short)((u + 0x7FFFu + ((u >> 16) & 1u)) >> 16);
}

// ---------- pre-pass: x (f32) -> bf16 ----------

__global__ void lb_cvt_x(const float* __restrict__ x, ushort8* __restrict__ xb, long n8) {
    long i = (long)blockIdx.x * blockDim.x + threadIdx.x;
    long stride = (long)gridDim.x * blockDim.x;
    for (; i < n8; i += stride) {
        const float4* p = (const float4*)x + i * 2;
        float4 a = p[0], b = p[1];
        ushort8 r;
        r[0] = f2bf_rne(a.x); r[1] = f2bf_rne(a.y); r[2] = f2bf_rne(a.z); r[3] = f2bf_rne(a.w);
        r[4] = f2bf_rne(b.x); r[5] = f2bf_rne(b.y); r[6] = f2bf_rne(b.z); r[7] = f2bf_rne(b.w);
        xb[i] = r;
    }
}

// ---------- pre-pass: w (f32) -> binarized bf16 {0,1} ----------

__global__ void lb_bin_w(const float* __restrict__ w, ushort8* __restrict__ wb, long n8) {
    long i = (long)blockIdx.x * blockDim.x + threadIdx.x;
    long stride = (long)gridDim.x * blockDim.x;
    for (; i < n8; i += stride) {
        const float4* p = (const float4*)w + i * 2;
        float4 a = p[0], b = p[1];
        ushort8 r;
        r[0] = (a.x > 0.5f) ? 0x3F80u : 0u; r[1] = (a.y > 0.5f) ? 0x3F80u : 0u;
        r[2] = (a.z > 0.5f) ? 0x3F80u : 0u; r[3] = (a.w > 0.5f) ? 0x3F80u : 0u;
        r[4] = (b.x > 0.5f) ? 0x3F80u : 0u; r[5] = (b.y > 0.5f) ? 0x3F80u : 0u;
        r[6] = (b.z > 0.5f) ? 0x3F80u : 0u; r[7] = (b.w > 0.5f) ? 0x3F80u : 0u;
        wb[i] = r;
    }
}

// ---------- main GEMM: 256x256 tile, BK=64, 8 waves, deep pipeline ----------
// LDS: 2(dbuf) x (A 256x64 + B 256x64) bf16 = 128 KiB. Granule swizzle g^=(r&7)
// applied on BOTH the pre-swizzled global source of global_load_lds (linear LDS
// dest) and the ds_read_b128 addresses. Counted vmcnt(8): K-tile t+2's 8 loads
// stay in flight across the barrier. Raw s_barrier (no vmcnt(0) drain).

#define BM 256
#define BN 256
#define BK 64

#define QUAD(MH, NH) do { \
    __builtin_amdgcn_s_setprio(1); \
    _Pragma("unroll") \
    for (int m_ = 0; m_ < 4; ++m_) { \
      _Pragma("unroll") \
      for (int n_ = 0; n_ < 2; ++n_) { \
        acc[(MH)*4+m_][(NH)*2+n_] = __builtin_amdgcn_mfma_f32_16x16x32_bf16( \
            af[(MH)*4+m_][0], bf[(NH)*2+n_][0], acc[(MH)*4+m_][(NH)*2+n_], 0,0,0); \
        acc[(MH)*4+m_][(NH)*2+n_] = __builtin_amdgcn_mfma_f32_16x16x32_bf16( \
            af[(MH)*4+m_][1], bf[(NH)*2+n_][1], acc[(MH)*4+m_][(NH)*2+n_], 0,0,0); \
      } \
    } \
    __builtin_amdgcn_s_setprio(0); \
} while (0)

__global__ __launch_bounds__(512, 2) void lb_gemm256(
    const unsigned short* __restrict__ A,  // M x K bf16 bits
    const unsigned short* __restrict__ B,  // N x K bf16 bits (binarized weight)
    const float* __restrict__ bias,
    float* __restrict__ C,
    int M, int N, int K)
{
    __shared__ unsigned short ldsA[2][BM * BK];   // 2 x 32 KiB
    __shared__ unsigned short ldsB[2][BN * BK];   // 2 x 32 KiB

    const int tid  = threadIdx.x;
    const int lane = tid & 63;
    const int wave = tid >> 6;       // 0..7
    const int wr   = wave >> 2;      // 0..1  -> 128 output rows
    const int wc   = wave & 3;       // 0..3  -> 64 output cols

    // XCD-aware bijective swizzle (grid % 8 == 0 guaranteed by launcher)
    int nwg = gridDim.x;
    int bid = blockIdx.x;
    bid = (bid & 7) * (nwg >> 3) + (bid >> 3);

    const int ntiles = N / BN;
    const int brow = (bid / ntiles) * BM;
    const int bcol = (bid % ntiles) * BN;

    const unsigned short* Abase = A + (size_t)brow * K;
    const unsigned short* Bbase = B + (size_t)bcol * K;

    const int wbase = wave * 512;    // element offset of wave inside a stage issue

    // one stage issue: 512 threads x 16B cover granules c*512 .. c*512+511
    // linear LDS granule G -> row r=G>>3, slot g=G&7; fetch logical granule g^(r&7)
    auto stage = [&](const unsigned short* gbase, unsigned short* lbase, int kt, int c) {
        int Gr = c * 512 + tid;
        int r  = Gr >> 3;
        int gl = (Gr & 7) ^ (r & 7);
        const unsigned short* src = gbase + (size_t)r * K + (size_t)kt * BK + gl * 8;
        unsigned short* dst = lbase + c * 4096 + wbase;
        __builtin_amdgcn_global_load_lds(
            (const __attribute__((address_space(1))) void*)src,
            (__attribute__((address_space(3))) void*)dst, 16, 0, 0);
    };

    // fragment addressing: row = (wr*128|wc*64) + frag*16 + fr ; row&7 == fr&7
    const int fr = lane & 15;
    const int fq = lane >> 4;
    const int sg0 = (fq)     ^ (fr & 7);   // stored granule, kk=0
    const int sg1 = (4 + fq) ^ (fr & 7);   // stored granule, kk=1

    f32x4 acc[8][4];
#pragma unroll
    for (int i = 0; i < 8; ++i)
#pragma unroll
        for (int j = 0; j < 4; ++j)
            acc[i][j] = (f32x4){0.f, 0.f, 0.f, 0.f};

    const int nk = K / BK;

    // prologue: stage K-tiles 0 and 1; wait until tile 0 done (tile 1 in flight)
#pragma unroll
    for (int c = 0; c < 4; ++c) stage(Abase, ldsA[0], 0, c);
#pragma unroll
    for (int c = 0; c < 4; ++c) stage(Bbase, ldsB[0], 0, c);
#pragma unroll
    for (int c = 0; c < 4; ++c) stage(Abase, ldsA[1], 1, c);
#pragma unroll
    for (int c = 0; c < 4; ++c) stage(Bbase, ldsB[1], 1, c);
    asm volatile("s_waitcnt vmcnt(8)" ::: "memory");
    __builtin_amdgcn_s_barrier();
    asm volatile("" ::: "memory");

    short8 af[8][2], bf[4][2];

    for (int t = 0; t < nk; ++t) {
        const int p = t & 1;
        const unsigned short* ap = &ldsA[p][(wr * 128 + fr) * BK];
        const unsigned short* bp = &ldsB[p][(wc * 64 + fr) * BK];

        // read ALL fragments of K-tile t into registers (24 x ds_read_b128)
#pragma unroll
        for (int m = 0; m < 8; ++m) {
            af[m][0] = *(const short8*)(ap + m * 16 * BK + sg0 * 8);
            af[m][1] = *(const short8*)(ap + m * 16 * BK + sg1 * 8);
        }
#pragma unroll
        for (int n = 0; n < 4; ++n) {
            bf[n][0] = *(const short8*)(bp + n * 16 * BK + sg0 * 8);
            bf[n][1] = *(const short8*)(bp + n * 16 * BK + sg1 * 8);
        }
        // my reads complete -> barrier -> every wave's reads complete:
        // buffer p is now dead, safe to overwrite with K-tile t+2
        asm volatile("s_waitcnt lgkmcnt(0)" ::: "memory");
        __builtin_amdgcn_s_barrier();
        asm volatile("" ::: "memory");

        const bool pf = (t + 2 < nk);
        const int ktn = t + 2;

        QUAD(0, 0);
        if (pf) { stage(Abase, ldsA[p], ktn, 0); stage(Abase, ldsA[p], ktn, 1);
                  stage(Abase, ldsA[p], ktn, 2); }
        QUAD(0, 1);
        if (pf) { stage(Abase, ldsA[p], ktn, 3); stage(Bbase, ldsB[p], ktn, 0);
                  stage(Bbase, ldsB[p], ktn, 1); }
        QUAD(1, 0);
        if (pf) { stage(Bbase, ldsB[p], ktn, 2); stage(Bbase, ldsB[p], ktn, 3); }
        QUAD(1, 1);

        if (t < nk - 1) {
            // drain K-tile t+1's 8 loads; leave t+2's 8 in flight (counted!)
            if (pf) asm volatile("s_waitcnt vmcnt(8)" ::: "memory");
            else    asm volatile("s_waitcnt vmcnt(0)" ::: "memory");
            __builtin_amdgcn_s_barrier();
            asm volatile("" ::: "memory");
        }
    }

    // epilogue: C/D layout col = lane&15, row = (lane>>4)*4 + reg  [m89/m91]
    float bn[4];
#pragma unroll
    for (int n = 0; n < 4; ++n)
        bn[n] = bias[bcol + wc * 64 + n * 16 + fr];

#pragma unroll
    for (int m = 0; m < 8; ++m) {
#pragma unroll
        for (int n = 0; n < 4; ++n) {
#pragma unroll
            for (int j = 0; j < 4; ++j) {
                int row = brow + wr * 128 + m * 16 + fq * 4 + j;
                int col = bcol + wc * 64 + n * 16 + fr;
                C[(size_t)row * N + col] = acc[m][n][j] + bn[n];
            }
        }
    }
}

// ---------- fallback: correct fp32 tiled GEMM ----------

__global__ __launch_bounds__(256) void lb_gemm_fb(
    const float* __restrict__ x, const float* __restrict__ w,
    const float* __restrict__ bias, float* __restrict__ C,
    int M, int N, int K)
{
    __shared__ float As[16][65];
    __shared__ float Bs[16][65];
    const int tid = threadIdx.x;
    const int tx = tid & 15, ty = tid >> 4;
    const int brow = blockIdx.y * 64, bcol = blockIdx.x * 64;

    float acc[4][4] = {};
    for (int kt = 0; kt < K; kt += 16) {
        for (int i = tid; i < 64 * 16; i += 256) {
            int r = i >> 4, k = i & 15;
            As[k][r] = x[(long)(brow + r) * K + kt + k];
        }
        for (int i = tid; i < 64 * 16; i += 256) {
            int n = i >> 4, k = i & 15;
            Bs[k][n] = (w[(long)(bcol + n) * K + kt + k] > 0.5f) ? 1.f : 0.f;
        }
        __syncthreads();
#pragma unroll
        for (int k = 0; k < 16; ++k) {
            float a[4], b[4];
#pragma unroll
            for (int i = 0; i < 4; ++i) a[i] = As[k][ty * 4 + i];
#pragma unroll
            for (int j = 0; j < 4; ++j) b[j] = Bs[k][tx * 4 + j];
#pragma unroll
            for (int i = 0; i < 4; ++i)
#pragma unroll
                for (int j = 0; j < 4; ++j)
                    acc[i][j] += a[i] * b[j];
        }
        __syncthreads();
    }
#pragma unroll
    for (int i = 0; i < 4; ++i)
#pragma unroll
        for (int j = 0; j < 4; ++j)
            C[(long)(brow + ty * 4 + i) * N + bcol + tx * 4 + j] = acc[i][j] + bias[bcol + tx * 4 + j];
}

// ---------- launcher ----------

extern "C" void kernel_launch(void* const* d_in, const int* in_sizes, int n_in,
                              void* d_out, int out_size, void* d_ws, size_t ws_size,
                              hipStream_t stream) {
    const float* x    = (const float*)d_in[0];
    const float* w    = (const float*)d_in[1];
    const float* bias = (const float*)d_in[2];
    float* out = (float*)d_out;

    const int N = in_sizes[2];                 // 4096
    const int K = in_sizes[1] / N;             // 4096
    const int M = in_sizes[0] / K;             // 8192

    const size_t need = ((size_t)M * K + (size_t)N * K) * sizeof(unsigned short);
    const int ngrid = (M / BM) * (N / BN);     // 32*16 = 512
    const bool ok = (ws_size >= need) && (M % BM == 0) && (N % BN == 0)
                    && (K % BK == 0) && (K / BK >= 3) && (ngrid % 8 == 0);

    if (ok) {
        unsigned short* xb = (unsigned short*)d_ws;
        unsigned short* wb = xb + (size_t)M * K;

        long nx8 = (long)M * K / 8;
        long nw8 = (long)N * K / 8;
        lb_cvt_x<<<2048, 256, 0, stream>>>(x, (ushort8*)xb, nx8);
        lb_bin_w<<<2048, 256, 0, stream>>>(w, (ushort8*)wb, nw8);

        lb_gemm256<<<dim3(ngrid), 512, 0, stream>>>(xb, wb, bias, out, M, N, K);
    } else {
        dim3 grid(N / 64, M / 64);
        lb_gemm_fb<<<grid, 256, 0, stream>>>(x, w, bias, out, M, N, K);
    }
}